// Round 1
// 50.244 us; speedup vs baseline: 1.1584x; 1.1584x over previous
//
#include <hip/hip_runtime.h>
#include <cstddef>

#define CTXDIM 256
#define RANK 8
#define KW 7
#define SCALE 0.17677669529663687f
#define NPIX 16384
#define PLANE16 (NPIX * 128)   // elems per fp16 qkv plane
#define WSTRIDE 136            // fp16 LDS tile stride for GEMM staging

typedef _Float16 half8 __attribute__((ext_vector_type(8)));
typedef _Float16 half2_t __attribute__((ext_vector_type(2)));
typedef float floatx4 __attribute__((ext_vector_type(4)));
typedef float floatx16 __attribute__((ext_vector_type(16)));
typedef int intx4 __attribute__((ext_vector_type(4)));

struct Params {
  const float *x, *ctx, *Wqkv, *bqkv, *A, *Blora, *Vlora;
  const float *g1w, *g1b, *g2w, *g2b, *Wproj, *bproj;
  float* out;
  _Float16* qkv16;   // planar fp16 [3][N][128]
  _Float16* at16;    // attention output fp16 [N][128]
};

// ---- cal[b][r] = alpha_b * (ctx[b] @ Blora)[r]; wave b handles batch b ----
__device__ __forceinline__ void compute_cal(const Params& p, int tid,
                                            float* cal_s) {
  const int b = tid >> 6, lane = tid & 63;
  const float c0 = p.ctx[b * CTXDIM + lane];
  const float c1 = p.ctx[b * CTXDIM + 64 + lane];
  const float c2 = p.ctx[b * CTXDIM + 128 + lane];
  const float c3 = p.ctx[b * CTXDIM + 192 + lane];
  float cp[RANK];
#pragma unroll
  for (int r = 0; r < RANK; ++r) {
    float q = c0 * p.Blora[lane * RANK + r] + c1 * p.Blora[(64 + lane) * RANK + r] +
              c2 * p.Blora[(128 + lane) * RANK + r] + c3 * p.Blora[(192 + lane) * RANK + r];
#pragma unroll
    for (int s = 32; s; s >>= 1) q += __shfl_xor(q, s, 64);
    cp[r] = q;
  }
  float gacc = 0.f;
#pragma unroll
  for (int h = 0; h < 16; ++h) {
    float q = c0 * p.g1w[h * CTXDIM + lane] + c1 * p.g1w[h * CTXDIM + 64 + lane] +
              c2 * p.g1w[h * CTXDIM + 128 + lane] + c3 * p.g1w[h * CTXDIM + 192 + lane];
#pragma unroll
    for (int s = 32; s; s >>= 1) q += __shfl_xor(q, s, 64);
    gacc += fmaxf(q + p.g1b[h], 0.f) * p.g2w[h];
  }
  if (lane == 0) {
    const float alpha = 1.f / (1.f + __expf(-(gacc + p.g2b[0])));
#pragma unroll
    for (int r = 0; r < RANK; ++r) cal_s[b * RANK + r] = alpha * cp[r];
  }
}

// ---- stage 64 fp32 rows (row stride 128) -> LDS fp16 [64][WSTRIDE] ----
__device__ __forceinline__ void stage_rows_f16(const float* __restrict__ src,
                                               _Float16* dst, int tid) {
  const int row = tid >> 2;
  const int c0 = (tid & 3) * 32;
  const float* sp = src + (size_t)row * 128 + c0;
  _Float16* dp = dst + row * WSTRIDE + c0;
#pragma unroll
  for (int i = 0; i < 4; ++i) {
    const float4 a = *(const float4*)(sp + i * 8);
    const float4 b = *(const float4*)(sp + i * 8 + 4);
    half8 o;
    o[0] = (_Float16)a.x; o[1] = (_Float16)a.y;
    o[2] = (_Float16)a.z; o[3] = (_Float16)a.w;
    o[4] = (_Float16)b.x; o[5] = (_Float16)b.y;
    o[6] = (_Float16)b.z; o[7] = (_Float16)b.w;
    *(half8*)(dp + i * 8) = o;
  }
}

// ---------------------------------------------------------------------------
// K1: QKV GEMM (unchanged from 58us version).
// ---------------------------------------------------------------------------
__global__ __launch_bounds__(256) void gemm1_kernel(Params p) {
  __shared__ __align__(16) _Float16 xs[64 * WSTRIDE];
  __shared__ __align__(16) _Float16 wsh[64 * WSTRIDE];
  __shared__ float cal_s[32];
  const int tid = threadIdx.x;
  const int bx = blockIdx.x, byg = blockIdx.y, z = blockIdx.z;
  const int m0 = z * 4096 + bx * 64;

  compute_cal(p, tid, cal_s);
  stage_rows_f16(p.x + (size_t)m0 * 128, xs, tid);
  __syncthreads();

  const int lane = tid & 63;
  const int w = tid >> 6;
  const int r = lane & 15;
  const int quad = lane >> 4;
  const int k = tid & 127;
  const int hgrp = tid >> 7;
  const float4 a0 = *(const float4*)&p.A[k * RANK];
  const float4 a1 = *(const float4*)&p.A[k * RANK + 4];
  const float* cb = &cal_s[z * RANK];
  const float c0 = cb[0], c1 = cb[1], c2 = cb[2], c3 = cb[3];
  const float c4 = cb[4], c5 = cb[5], c6 = cb[6], c7 = cb[7];

  for (int i = 0; i < 3; ++i) {
    const int n0 = (byg * 3 + i) * 64;

#pragma unroll
    for (int rr = 0; rr < 32; ++rr) {
      const int row = hgrp * 32 + rr;
      const int o = n0 + row;
      const float4 v0 = *(const float4*)&p.Vlora[o * RANK];
      const float4 v1 = *(const float4*)&p.Vlora[o * RANK + 4];
      float d = a0.x * v0.x * c0;
      d = fmaf(a0.y * v0.y, c1, d);
      d = fmaf(a0.z * v0.z, c2, d);
      d = fmaf(a0.w * v0.w, c3, d);
      d = fmaf(a1.x * v1.x, c4, d);
      d = fmaf(a1.y * v1.y, c5, d);
      d = fmaf(a1.z * v1.z, c6, d);
      d = fmaf(a1.w * v1.w, c7, d);
      wsh[row * WSTRIDE + k] = (_Float16)(p.Wqkv[o * 128 + k] + d);
    }
    __syncthreads();

    const _Float16* ap = xs + (w * 16 + r) * WSTRIDE + quad * 8;
    const _Float16* bp = wsh + r * WSTRIDE + quad * 8;
    floatx4 acc0 = {0.f, 0.f, 0.f, 0.f};
    floatx4 acc1 = acc0, acc2 = acc0, acc3 = acc0;
#pragma unroll
    for (int kc = 0; kc < 4; ++kc) {
      const half8 a  = *(const half8*)(ap + kc * 32);
      const half8 b0 = *(const half8*)(bp + kc * 32);
      const half8 b1 = *(const half8*)(bp + 16 * WSTRIDE + kc * 32);
      const half8 b2 = *(const half8*)(bp + 32 * WSTRIDE + kc * 32);
      const half8 b3 = *(const half8*)(bp + 48 * WSTRIDE + kc * 32);
      acc0 = __builtin_amdgcn_mfma_f32_16x16x32_f16(a, b0, acc0, 0, 0, 0);
      acc1 = __builtin_amdgcn_mfma_f32_16x16x32_f16(a, b1, acc1, 0, 0, 0);
      acc2 = __builtin_amdgcn_mfma_f32_16x16x32_f16(a, b2, acc2, 0, 0, 0);
      acc3 = __builtin_amdgcn_mfma_f32_16x16x32_f16(a, b3, acc3, 0, 0, 0);
    }

    const int mbase = m0 + w * 16 + quad * 4;
    floatx4 accs[4] = {acc0, acc1, acc2, acc3};
#pragma unroll
    for (int nt = 0; nt < 4; ++nt) {
      const int ncol = n0 + nt * 16 + r;
      const float bv = p.bqkv[ncol];
      _Float16* cp = p.qkv16 + (size_t)(ncol >> 7) * PLANE16 +
                     (size_t)mbase * 128 + (ncol & 127);
#pragma unroll
      for (int reg = 0; reg < 4; ++reg)
        cp[(size_t)reg * 128] = (_Float16)(accs[nt][reg] + bv);
    }
    if (i != 2) __syncthreads();
  }
}

// ---------------------------------------------------------------------------
// K2 v2: MFMA neighborhood attention.
// Block = (b,ti,tj,h), 128 threads = 2 waves; wave w owns pixel rows 4w..4w+3.
// Halo stored at hp' = hr*16 + hc (bit-decodable); K row-major [224][40],
// V transposed+swizzled [32][256] (xor-8-block by sig(d)).
// Swapped QK^T: S^T = K*Q^T via mfma_32x32x16_f16 -> lane owns one pixel's
// logit column; softmax lane-local + 1 shfl_xor(32). P stays in registers:
// fp16 packs + 4 shfl_xor(32) + selects rebuild PV A-fragments per K-step.
// Each wave touches only the 5 hp-tiles its rows can see (MT0 = 0 or 2).
// ---------------------------------------------------------------------------
__device__ __forceinline__ int vta(int d, int k) {
  const int sig = (d + (d >> 3)) & 7;
  return d * 256 + (((k >> 3) ^ sig) << 3) + (k & 7);
}

__device__ __forceinline__ int packh(float x, float y) {
  half2_t h;
  h[0] = (_Float16)x;
  h[1] = (_Float16)y;
  return __builtin_bit_cast(int, h);
}

template <int MT0, int W>
__device__ __forceinline__ void attn_wave(const Params& p,
                                          const _Float16* kls,
                                          const _Float16* vtl,
                                          half8 qb0, half8 qb1,
                                          int m31, int l5, int pi, int pj,
                                          int b, int ti, int tj, int h) {
  // ---- QK^T: 5 M-tiles of 32 halo rows, K = 32 dims (2 mfma steps) ----
  const floatx16 zz = {0.f,0.f,0.f,0.f,0.f,0.f,0.f,0.f,
                       0.f,0.f,0.f,0.f,0.f,0.f,0.f,0.f};
  floatx16 acc[5];
#pragma unroll
  for (int mt = 0; mt < 5; ++mt) {
    const int Mt = MT0 + mt;
    const half8 ka0 = *(const half8*)&kls[(Mt * 32 + m31) * 40 + l5 * 8];
    const half8 ka1 = *(const half8*)&kls[(Mt * 32 + m31) * 40 + 16 + l5 * 8];
    floatx16 a = zz;
    a = __builtin_amdgcn_mfma_f32_32x32x16_f16(ka0, qb0, a, 0, 0, 0);
    a = __builtin_amdgcn_mfma_f32_32x32x16_f16(ka1, qb1, a, 0, 0, 0);
    acc[mt] = a;
  }

  // ---- validity lookups: hr = 2*Mt + (reg>>3); hc = (reg&3)+8*((reg>>2)&1)+4*l5
  bool vR[14];
#pragma unroll
  for (int i = 0; i < 14; ++i) vR[i] = (unsigned)(i - pi) < 7u;
  bool vC[8];
#pragma unroll
  for (int c8 = 0; c8 < 8; ++c8) {
    const int hcv = (c8 & 3) + 8 * (c8 >> 2) + 4 * l5;
    vC[c8] = (unsigned)(hcv - pj) < 7u;
  }

  // ---- mask + row max (lane-local column of S^T, + partner half) ----
  float mxp[4] = {-1e30f, -1e30f, -1e30f, -1e30f};
#pragma unroll
  for (int mt = 0; mt < 5; ++mt) {
#pragma unroll
    for (int reg = 0; reg < 16; ++reg) {
      const bool v = vR[2 * (MT0 + mt) + (reg >> 3)] &&
                     vC[(reg & 3) + 4 * ((reg >> 2) & 1)];
      const float x = v ? acc[mt][reg] : -1e30f;
      acc[mt][reg] = x;
      mxp[reg & 3] = fmaxf(mxp[reg & 3], x);
    }
  }
  float mx = fmaxf(fmaxf(mxp[0], mxp[1]), fmaxf(mxp[2], mxp[3]));
  mx = fmaxf(mx, __shfl_xor(mx, 32, 64));

  // ---- exp + sum (softmax over raw logits * SCALE, algebra folded) ----
  const float SC2 = SCALE * 1.4426950408889634f;  // to exp2
  float sp[4] = {0.f, 0.f, 0.f, 0.f};
#pragma unroll
  for (int mt = 0; mt < 5; ++mt) {
#pragma unroll
    for (int reg = 0; reg < 16; ++reg) {
      const float pv = exp2f((acc[mt][reg] - mx) * SC2);
      acc[mt][reg] = pv;
      sp[reg & 3] += pv;
    }
  }
  float sum = (sp[0] + sp[1]) + (sp[2] + sp[3]);
  sum += __shfl_xor(sum, 32, 64);
  const float inv = 1.f / sum;

  // ---- PV: out[pix][d] = P * V, A-frag rebuilt from registers ----
  floatx16 oacc = zz;
  const int sigd = (m31 + (m31 >> 3)) & 7;
  const int vbase = m31 * 256;
#pragma unroll
  for (int kk = 0; kk < 10; ++kk) {
    const int ks = MT0 * 2 + kk;        // k-step: hp = ks*16 + l5*8 + e
    const int mt = (ks >> 1) - MT0;
    const int r8 = 8 * (ks & 1);
    // E[l5t][jj] = pack of (hp, hp+1), hp = 16ks + 8*l5t + 2jj + 4*l5(lane)
    const int E00 = packh(acc[mt][r8 + 0] * inv, acc[mt][r8 + 1] * inv);
    const int E01 = packh(acc[mt][r8 + 2] * inv, acc[mt][r8 + 3] * inv);
    const int E10 = packh(acc[mt][r8 + 4] * inv, acc[mt][r8 + 5] * inv);
    const int E11 = packh(acc[mt][r8 + 6] * inv, acc[mt][r8 + 7] * inv);
    const int R00 = __shfl_xor(E00, 32, 64);
    const int R01 = __shfl_xor(E01, 32, 64);
    const int R10 = __shfl_xor(E10, 32, 64);
    const int R11 = __shfl_xor(E11, 32, 64);
    const int A0 = l5 ? R10 : E00;
    const int A1 = l5 ? R11 : E01;
    const int A2 = l5 ? E10 : R00;
    const int A3 = l5 ? E11 : R01;
    const intx4 ai = {A0, A1, A2, A3};
    const half8 af = __builtin_bit_cast(half8, ai);
    const half8 vb = *(const half8*)&vtl[vbase + (((2 * ks + l5) ^ sigd) << 3)];
    oacc = __builtin_amdgcn_mfma_f32_32x32x16_f16(af, vb, oacc, 0, 0, 0);
  }

  // ---- write at16: C rows = pixel, cols = dim ----
#pragma unroll
  for (int reg = 0; reg < 16; ++reg) {
    const int rowM = (reg & 3) + 8 * (reg >> 2) + 4 * l5;
    const int pxt = W * 32 + rowM;
    const int n = b * 4096 + (ti * 8 + (pxt >> 3)) * 64 + tj * 8 + (pxt & 7);
    p.at16[(size_t)n * 128 + h * 32 + m31] = (_Float16)oacc[reg];
  }
}

__global__ __launch_bounds__(128, 2) void attn_kernel(Params p) {
  __shared__ __align__(16) _Float16 kls[224 * 40];   // 17.9 KB
  __shared__ __align__(16) _Float16 vtl[32 * 256];   // 16.4 KB

  const int bid = blockIdx.x;        // [0,1024)
  const int h  = bid & 3;
  const int tj = (bid >> 2) & 7;
  const int ti = (bid >> 5) & 7;
  const int b  = bid >> 8;
  const int tid = threadIdx.x;
  const int lane = tid & 63;
  const int w = tid >> 6;
  const int m31 = lane & 31;
  const int l5 = lane >> 5;

  const _Float16* kpl = p.qkv16 + PLANE16;
  const _Float16* vpl = p.qkv16 + 2 * (size_t)PLANE16;

  // ---- hoisted Q B-fragments (pix = w*32 + m31) ----
  const int pix = w * 32 + m31;
  const int pi = pix >> 3, pj = pix & 7;
  const int nq = b * 4096 + (ti * 8 + pi) * 64 + tj * 8 + pj;
  const half8 qb0 = *(const half8*)(p.qkv16 + (size_t)nq * 128 + h * 32 + l5 * 8);
  const half8 qb1 = *(const half8*)(p.qkv16 + (size_t)nq * 128 + h * 32 + 16 + l5 * 8);

  // ---- zero Vt holes: k with (k&15) in {14,15}, k <= 223, all 32 dims ----
  for (int idx = tid; idx < 896; idx += 128) {
    const int d = idx & 31;
    const int kk = idx >> 5;                 // 0..27
    const int k = (kk >> 1) * 16 + 14 + (kk & 1);
    vtl[vta(d, k)] = (_Float16)0.f;
  }

  // ---- stage K rows (hp' = hr*16+hc) and transposed-swizzled V ----
  const int i0 = ti * 8 - 3;
  const int j0 = tj * 8 - 3;
  for (int s = tid; s < 784; s += 128) {
    const int pp = s >> 2;                   // halo pixel 0..195
    const int d8 = (s & 3) * 8;
    const int hr = pp / 14;
    const int hc = pp - hr * 14;
    const int row = hr * 16 + hc;
    const int ii = i0 + hr;
    const int jj = j0 + hc;
    half8 kv = {0, 0, 0, 0, 0, 0, 0, 0};
    half8 vv = {0, 0, 0, 0, 0, 0, 0, 0};
    if ((unsigned)ii < 64u && (unsigned)jj < 64u) {
      const size_t g = (size_t)(b * 4096 + ii * 64 + jj) * 128 + h * 32 + d8;
      kv = *(const half8*)(kpl + g);
      vv = *(const half8*)(vpl + g);
    }
    *(half8*)&kls[row * 40 + d8] = kv;
#pragma unroll
    for (int e = 0; e < 8; ++e)
      vtl[vta(d8 + e, row)] = vv[e];
  }
  __syncthreads();

  if (w == 0)
    attn_wave<0, 0>(p, kls, vtl, qb0, qb1, m31, l5, pi, pj, b, ti, tj, h);
  else
    attn_wave<2, 1>(p, kls, vtl, qb0, qb1, m31, l5, pi, pj, b, ti, tj, h);
}

// ---------------------------------------------------------------------------
// K3: projection GEMM (unchanged).
// ---------------------------------------------------------------------------
__global__ __launch_bounds__(256) void gemm2_kernel(Params p) {
  __shared__ __align__(16) _Float16 wsh[64 * WSTRIDE];
  const int tid = threadIdx.x;
  const int m0 = blockIdx.x * 64;
  const int n0 = blockIdx.y * 64;

  stage_rows_f16(p.Wproj + (size_t)n0 * 128, wsh, tid);
  __syncthreads();

  const int lane = tid & 63;
  const int w = tid >> 6;
  const int r = lane & 15;
  const int quad = lane >> 4;
  const _Float16* ap = p.at16 + (size_t)(m0 + w * 16 + r) * 128 + quad * 8;
  const _Float16* bp = wsh + r * WSTRIDE + quad * 8;

  floatx4 acc0 = {0.f, 0.f, 0.f, 0.f};
  floatx4 acc1 = acc0, acc2 = acc0, acc3 = acc0;
#pragma unroll
  for (int kc = 0; kc < 4; ++kc) {
    const half8 a  = *(const half8*)(ap + kc * 32);
    const half8 b0 = *(const half8*)(bp + kc * 32);
    const half8 b1 = *(const half8*)(bp + 16 * WSTRIDE + kc * 32);
    const half8 b2 = *(const half8*)(bp + 32 * WSTRIDE + kc * 32);
    const half8 b3 = *(const half8*)(bp + 48 * WSTRIDE + kc * 32);
    acc0 = __builtin_amdgcn_mfma_f32_16x16x32_f16(a, b0, acc0, 0, 0, 0);
    acc1 = __builtin_amdgcn_mfma_f32_16x16x32_f16(a, b1, acc1, 0, 0, 0);
    acc2 = __builtin_amdgcn_mfma_f32_16x16x32_f16(a, b2, acc2, 0, 0, 0);
    acc3 = __builtin_amdgcn_mfma_f32_16x16x32_f16(a, b3, acc3, 0, 0, 0);
  }

  const int mbase = m0 + w * 16 + quad * 4;
  floatx4 accs[4] = {acc0, acc1, acc2, acc3};
#pragma unroll
  for (int nt = 0; nt < 4; ++nt) {
    const int n = n0 + nt * 16 + r;
    const float bv = p.bproj[n];
    float* cp = p.out + (size_t)mbase * 128 + n;
#pragma unroll
    for (int reg = 0; reg < 4; ++reg)
      cp[(size_t)reg * 128] = accs[nt][reg] + bv;
  }
}

// ---------------------------------------------------------------------------
// Workspace (18 MB):
//   [1 MB, 13 MB)   qkv16  [3][16384][128] fp16 planar
//   [14 MB, 18 MB)  at16   [16384][128] fp16
// ---------------------------------------------------------------------------
extern "C" void kernel_launch(void* const* d_in, const int* in_sizes, int n_in,
                              void* d_out, int out_size, void* d_ws, size_t ws_size,
                              hipStream_t stream) {
  char* ws = (char*)d_ws;
  Params hp;
  hp.x     = (const float*)d_in[0];
  hp.ctx   = (const float*)d_in[1];
  hp.Wqkv  = (const float*)d_in[2];
  hp.bqkv  = (const float*)d_in[3];
  hp.A     = (const float*)d_in[4];
  hp.Blora = (const float*)d_in[5];
  hp.Vlora = (const float*)d_in[6];
  hp.g1w   = (const float*)d_in[7];
  hp.g1b   = (const float*)d_in[8];
  hp.g2w   = (const float*)d_in[9];
  hp.g2b   = (const float*)d_in[10];
  hp.Wproj = (const float*)d_in[11];
  hp.bproj = (const float*)d_in[12];
  hp.out   = (float*)d_out;
  hp.qkv16 = (_Float16*)(ws + (1u << 20));
  hp.at16  = (_Float16*)(ws + (14u << 20));

  gemm1_kernel<<<dim3(64, 2, 4), 256, 0, stream>>>(hp);
  attn_kernel<<<1024, 128, 0, stream>>>(hp);
  gemm2_kernel<<<dim3(256, 2), 256, 0, stream>>>(hp);
}

// Round 2
// 49.299 us; speedup vs baseline: 1.1806x; 1.0192x over previous
//
#include <hip/hip_runtime.h>
#include <cstddef>

#define CTXDIM 256
#define RANK 8
#define KW 7
#define SCALE 0.17677669529663687f
#define NPIX 16384
#define PLANE16 (NPIX * 128)   // elems per fp16 qkv plane
#define WSTRIDE 136            // fp16 LDS tile stride for GEMM staging

// fused attn+proj LDS layout (fp16 element offsets):
#define KHEAD 8960             // 224*40 K-halo per head
#define VHEAD 8192             // 32*256 V^T per head
#define VBASE (4 * KHEAD)      // 35840
// phase2 reuse: at_s = sm[0..8704) (inside K region),
//               wsh  = sm[VBASE..VBASE+17408) (inside V region)

typedef _Float16 half8 __attribute__((ext_vector_type(8)));
typedef _Float16 half2_t __attribute__((ext_vector_type(2)));
typedef float floatx4 __attribute__((ext_vector_type(4)));
typedef float floatx16 __attribute__((ext_vector_type(16)));
typedef int intx4 __attribute__((ext_vector_type(4)));

struct Params {
  const float *x, *ctx, *Wqkv, *bqkv, *A, *Blora, *Vlora;
  const float *g1w, *g1b, *g2w, *g2b, *Wproj, *bproj;
  float* out;
  _Float16* qkv16;   // planar fp16 [3][N][128]
  _Float16* at16;    // (unused in fused path)
};

// ---- cal[b][r] = alpha_b * (ctx[b] @ Blora)[r]; wave b handles batch b ----
__device__ __forceinline__ void compute_cal(const Params& p, int tid,
                                            float* cal_s) {
  const int b = tid >> 6, lane = tid & 63;
  const float c0 = p.ctx[b * CTXDIM + lane];
  const float c1 = p.ctx[b * CTXDIM + 64 + lane];
  const float c2 = p.ctx[b * CTXDIM + 128 + lane];
  const float c3 = p.ctx[b * CTXDIM + 192 + lane];
  float cp[RANK];
#pragma unroll
  for (int r = 0; r < RANK; ++r) {
    float q = c0 * p.Blora[lane * RANK + r] + c1 * p.Blora[(64 + lane) * RANK + r] +
              c2 * p.Blora[(128 + lane) * RANK + r] + c3 * p.Blora[(192 + lane) * RANK + r];
#pragma unroll
    for (int s = 32; s; s >>= 1) q += __shfl_xor(q, s, 64);
    cp[r] = q;
  }
  float gacc = 0.f;
#pragma unroll
  for (int h = 0; h < 16; ++h) {
    float q = c0 * p.g1w[h * CTXDIM + lane] + c1 * p.g1w[h * CTXDIM + 64 + lane] +
              c2 * p.g1w[h * CTXDIM + 128 + lane] + c3 * p.g1w[h * CTXDIM + 192 + lane];
#pragma unroll
    for (int s = 32; s; s >>= 1) q += __shfl_xor(q, s, 64);
    gacc += fmaxf(q + p.g1b[h], 0.f) * p.g2w[h];
  }
  if (lane == 0) {
    const float alpha = 1.f / (1.f + __expf(-(gacc + p.g2b[0])));
#pragma unroll
    for (int r = 0; r < RANK; ++r) cal_s[b * RANK + r] = alpha * cp[r];
  }
}

// ---- stage 64 fp32 rows (row stride 128) -> LDS fp16 [64][WSTRIDE] ----
__device__ __forceinline__ void stage_rows_f16(const float* __restrict__ src,
                                               _Float16* dst, int tid) {
  const int row = tid >> 2;
  const int c0 = (tid & 3) * 32;
  const float* sp = src + (size_t)row * 128 + c0;
  _Float16* dp = dst + row * WSTRIDE + c0;
#pragma unroll
  for (int i = 0; i < 4; ++i) {
    const float4 a = *(const float4*)(sp + i * 8);
    const float4 b = *(const float4*)(sp + i * 8 + 4);
    half8 o;
    o[0] = (_Float16)a.x; o[1] = (_Float16)a.y;
    o[2] = (_Float16)a.z; o[3] = (_Float16)a.w;
    o[4] = (_Float16)b.x; o[5] = (_Float16)b.y;
    o[6] = (_Float16)b.z; o[7] = (_Float16)b.w;
    *(half8*)(dp + i * 8) = o;
  }
}

// ---------------------------------------------------------------------------
// K1: QKV GEMM (unchanged, proven).
// ---------------------------------------------------------------------------
__global__ __launch_bounds__(256) void gemm1_kernel(Params p) {
  __shared__ __align__(16) _Float16 xs[64 * WSTRIDE];
  __shared__ __align__(16) _Float16 wsh[64 * WSTRIDE];
  __shared__ float cal_s[32];
  const int tid = threadIdx.x;
  const int bx = blockIdx.x, byg = blockIdx.y, z = blockIdx.z;
  const int m0 = z * 4096 + bx * 64;

  compute_cal(p, tid, cal_s);
  stage_rows_f16(p.x + (size_t)m0 * 128, xs, tid);
  __syncthreads();

  const int lane = tid & 63;
  const int w = tid >> 6;
  const int r = lane & 15;
  const int quad = lane >> 4;
  const int k = tid & 127;
  const int hgrp = tid >> 7;
  const float4 a0 = *(const float4*)&p.A[k * RANK];
  const float4 a1 = *(const float4*)&p.A[k * RANK + 4];
  const float* cb = &cal_s[z * RANK];
  const float c0 = cb[0], c1 = cb[1], c2 = cb[2], c3 = cb[3];
  const float c4 = cb[4], c5 = cb[5], c6 = cb[6], c7 = cb[7];

  for (int i = 0; i < 3; ++i) {
    const int n0 = (byg * 3 + i) * 64;

#pragma unroll
    for (int rr = 0; rr < 32; ++rr) {
      const int row = hgrp * 32 + rr;
      const int o = n0 + row;
      const float4 v0 = *(const float4*)&p.Vlora[o * RANK];
      const float4 v1 = *(const float4*)&p.Vlora[o * RANK + 4];
      float d = a0.x * v0.x * c0;
      d = fmaf(a0.y * v0.y, c1, d);
      d = fmaf(a0.z * v0.z, c2, d);
      d = fmaf(a0.w * v0.w, c3, d);
      d = fmaf(a1.x * v1.x, c4, d);
      d = fmaf(a1.y * v1.y, c5, d);
      d = fmaf(a1.z * v1.z, c6, d);
      d = fmaf(a1.w * v1.w, c7, d);
      wsh[row * WSTRIDE + k] = (_Float16)(p.Wqkv[o * 128 + k] + d);
    }
    __syncthreads();

    const _Float16* ap = xs + (w * 16 + r) * WSTRIDE + quad * 8;
    const _Float16* bp = wsh + r * WSTRIDE + quad * 8;
    floatx4 acc0 = {0.f, 0.f, 0.f, 0.f};
    floatx4 acc1 = acc0, acc2 = acc0, acc3 = acc0;
#pragma unroll
    for (int kc = 0; kc < 4; ++kc) {
      const half8 a  = *(const half8*)(ap + kc * 32);
      const half8 b0 = *(const half8*)(bp + kc * 32);
      const half8 b1 = *(const half8*)(bp + 16 * WSTRIDE + kc * 32);
      const half8 b2 = *(const half8*)(bp + 32 * WSTRIDE + kc * 32);
      const half8 b3 = *(const half8*)(bp + 48 * WSTRIDE + kc * 32);
      acc0 = __builtin_amdgcn_mfma_f32_16x16x32_f16(a, b0, acc0, 0, 0, 0);
      acc1 = __builtin_amdgcn_mfma_f32_16x16x32_f16(a, b1, acc1, 0, 0, 0);
      acc2 = __builtin_amdgcn_mfma_f32_16x16x32_f16(a, b2, acc2, 0, 0, 0);
      acc3 = __builtin_amdgcn_mfma_f32_16x16x32_f16(a, b3, acc3, 0, 0, 0);
    }

    const int mbase = m0 + w * 16 + quad * 4;
    floatx4 accs[4] = {acc0, acc1, acc2, acc3};
#pragma unroll
    for (int nt = 0; nt < 4; ++nt) {
      const int ncol = n0 + nt * 16 + r;
      const float bv = p.bqkv[ncol];
      _Float16* cp = p.qkv16 + (size_t)(ncol >> 7) * PLANE16 +
                     (size_t)mbase * 128 + (ncol & 127);
#pragma unroll
      for (int reg = 0; reg < 4; ++reg)
        cp[(size_t)reg * 128] = (_Float16)(accs[nt][reg] + bv);
    }
    if (i != 2) __syncthreads();
  }
}

// ---------------------------------------------------------------------------
// K2 fused: MFMA neighborhood attention + output projection, one kernel.
// Block = (b,ti,tj): 8x8 pixel tile, ALL 4 heads; 256 blocks (1/CU).
// Wave = head.  Each wave runs the proven swapped-QK^T attn for both pixel
// halves (MT0=0 rows 0-3, MT0=2 rows 4-7), keeps oacc in registers.
// Then: barrier -> at tile to LDS (dead K region), Wproj fp16 to LDS (dead
// V region) -> barrier -> 64x128x128 projection (K3 MFMA pattern) -> out.
// Eliminates the 8.4 MB at16 HBM round-trip + one launch gap.
// ---------------------------------------------------------------------------
__device__ __forceinline__ int vta(int d, int k) {
  const int sig = (d + (d >> 3)) & 7;
  return d * 256 + (((k >> 3) ^ sig) << 3) + (k & 7);
}

__device__ __forceinline__ int packh(float x, float y) {
  half2_t h;
  h[0] = (_Float16)x;
  h[1] = (_Float16)y;
  return __builtin_bit_cast(int, h);
}

template <int MT0>
__device__ __forceinline__ floatx16 attn_wave(const _Float16* kls,
                                              const _Float16* vtl,
                                              half8 qb0, half8 qb1,
                                              int m31, int l5, int pi, int pj) {
  // ---- QK^T: 5 M-tiles of 32 halo rows, K = 32 dims (2 mfma steps) ----
  const floatx16 zz = {0.f,0.f,0.f,0.f,0.f,0.f,0.f,0.f,
                       0.f,0.f,0.f,0.f,0.f,0.f,0.f,0.f};
  floatx16 acc[5];
#pragma unroll
  for (int mt = 0; mt < 5; ++mt) {
    const int Mt = MT0 + mt;
    const half8 ka0 = *(const half8*)&kls[(Mt * 32 + m31) * 40 + l5 * 8];
    const half8 ka1 = *(const half8*)&kls[(Mt * 32 + m31) * 40 + 16 + l5 * 8];
    floatx16 a = zz;
    a = __builtin_amdgcn_mfma_f32_32x32x16_f16(ka0, qb0, a, 0, 0, 0);
    a = __builtin_amdgcn_mfma_f32_32x32x16_f16(ka1, qb1, a, 0, 0, 0);
    acc[mt] = a;
  }

  // ---- validity: hr = 2*Mt + (reg>>3); hc = (reg&3)+8*((reg>>2)&1)+4*l5 ----
  bool vR[14];
#pragma unroll
  for (int i = 0; i < 14; ++i) vR[i] = (unsigned)(i - pi) < 7u;
  bool vC[8];
#pragma unroll
  for (int c8 = 0; c8 < 8; ++c8) {
    const int hcv = (c8 & 3) + 8 * (c8 >> 2) + 4 * l5;
    vC[c8] = (unsigned)(hcv - pj) < 7u;
  }

  float mxp[4] = {-1e30f, -1e30f, -1e30f, -1e30f};
#pragma unroll
  for (int mt = 0; mt < 5; ++mt) {
#pragma unroll
    for (int reg = 0; reg < 16; ++reg) {
      const bool v = vR[2 * (MT0 + mt) + (reg >> 3)] &&
                     vC[(reg & 3) + 4 * ((reg >> 2) & 1)];
      const float x = v ? acc[mt][reg] : -1e30f;
      acc[mt][reg] = x;
      mxp[reg & 3] = fmaxf(mxp[reg & 3], x);
    }
  }
  float mx = fmaxf(fmaxf(mxp[0], mxp[1]), fmaxf(mxp[2], mxp[3]));
  mx = fmaxf(mx, __shfl_xor(mx, 32, 64));

  const float SC2 = SCALE * 1.4426950408889634f;  // to exp2
  float sp[4] = {0.f, 0.f, 0.f, 0.f};
#pragma unroll
  for (int mt = 0; mt < 5; ++mt) {
#pragma unroll
    for (int reg = 0; reg < 16; ++reg) {
      const float pv = exp2f((acc[mt][reg] - mx) * SC2);
      acc[mt][reg] = pv;
      sp[reg & 3] += pv;
    }
  }
  float sum = (sp[0] + sp[1]) + (sp[2] + sp[3]);
  sum += __shfl_xor(sum, 32, 64);
  const float inv = 1.f / sum;

  // ---- PV: A-frag rebuilt from registers (packs + 4 xor-shuffles) ----
  floatx16 oacc = zz;
  const int sigd = (m31 + (m31 >> 3)) & 7;
  const int vbase = m31 * 256;
#pragma unroll
  for (int kk = 0; kk < 10; ++kk) {
    const int ks = MT0 * 2 + kk;
    const int mt = (ks >> 1) - MT0;
    const int r8 = 8 * (ks & 1);
    const int E00 = packh(acc[mt][r8 + 0] * inv, acc[mt][r8 + 1] * inv);
    const int E01 = packh(acc[mt][r8 + 2] * inv, acc[mt][r8 + 3] * inv);
    const int E10 = packh(acc[mt][r8 + 4] * inv, acc[mt][r8 + 5] * inv);
    const int E11 = packh(acc[mt][r8 + 6] * inv, acc[mt][r8 + 7] * inv);
    const int R00 = __shfl_xor(E00, 32, 64);
    const int R01 = __shfl_xor(E01, 32, 64);
    const int R10 = __shfl_xor(E10, 32, 64);
    const int R11 = __shfl_xor(E11, 32, 64);
    const int A0 = l5 ? R10 : E00;
    const int A1 = l5 ? R11 : E01;
    const int A2 = l5 ? E10 : R00;
    const int A3 = l5 ? E11 : R01;
    const intx4 ai = {A0, A1, A2, A3};
    const half8 af = __builtin_bit_cast(half8, ai);
    const half8 vb = *(const half8*)&vtl[vbase + (((2 * ks + l5) ^ sigd) << 3)];
    oacc = __builtin_amdgcn_mfma_f32_32x32x16_f16(af, vb, oacc, 0, 0, 0);
  }
  return oacc;
}

__global__ __launch_bounds__(256, 1) void attn_proj_kernel(Params p) {
  __shared__ __align__(16) _Float16 sm[4 * KHEAD + 4 * VHEAD];  // 134 KB

  const int bid = blockIdx.x;        // [0,256): b*64 + ti*8 + tj
  const int tj = bid & 7;
  const int ti = (bid >> 3) & 7;
  const int b  = bid >> 6;
  const int tid = threadIdx.x;
  const int h = tid >> 6;            // wave = head
  const int lane = tid & 63;
  const int m31 = lane & 31;
  const int l5 = lane >> 5;

  _Float16* kls = sm + h * KHEAD;
  _Float16* vtl = sm + VBASE + h * VHEAD;

  const _Float16* kpl = p.qkv16 + PLANE16;
  const _Float16* vpl = p.qkv16 + 2 * (size_t)PLANE16;

  // ---- hoisted Q fragments, both pixel halves (overlaps staging) ----
  const int pi0 = m31 >> 3, pj0 = m31 & 7;      // pix = m31
  const int pi1 = 4 + pi0, pj1 = pj0;           // pix = 32 + m31
  const int nq0 = b * 4096 + (ti * 8 + pi0) * 64 + tj * 8 + pj0;
  const int nq1 = nq0 + 4 * 64;
  const half8 q00 = *(const half8*)(p.qkv16 + (size_t)nq0 * 128 + h * 32 + l5 * 8);
  const half8 q01 = *(const half8*)(p.qkv16 + (size_t)nq0 * 128 + h * 32 + 16 + l5 * 8);
  const half8 q10 = *(const half8*)(p.qkv16 + (size_t)nq1 * 128 + h * 32 + l5 * 8);
  const half8 q11 = *(const half8*)(p.qkv16 + (size_t)nq1 * 128 + h * 32 + 16 + l5 * 8);

  // ---- zero V^T holes for own head: k%16 in {14,15} ----
  for (int idx = lane; idx < 896; idx += 64) {
    const int d = idx & 31;
    const int kk = idx >> 5;
    const int k = (kk >> 1) * 16 + 14 + (kk & 1);
    vtl[vta(d, k)] = (_Float16)0.f;
  }

  // ---- stage K rows (hp' = hr*16+hc) and transposed-swizzled V ----
  const int i0 = ti * 8 - 3;
  const int j0 = tj * 8 - 3;
  for (int s = lane; s < 784; s += 64) {
    const int pp = s >> 2;
    const int d8 = (s & 3) * 8;
    const int hr = pp / 14;
    const int hc = pp - hr * 14;
    const int row = hr * 16 + hc;
    const int ii = i0 + hr;
    const int jj = j0 + hc;
    half8 kv = {0, 0, 0, 0, 0, 0, 0, 0};
    half8 vv = {0, 0, 0, 0, 0, 0, 0, 0};
    if ((unsigned)ii < 64u && (unsigned)jj < 64u) {
      const size_t g = (size_t)(b * 4096 + ii * 64 + jj) * 128 + h * 32 + d8;
      kv = *(const half8*)(kpl + g);
      vv = *(const half8*)(vpl + g);
    }
    *(half8*)&kls[row * 40 + d8] = kv;
#pragma unroll
    for (int e = 0; e < 8; ++e)
      vtl[vta(d8 + e, row)] = vv[e];
  }
  __syncthreads();

  // ---- attention, both halves; results stay in registers ----
  const floatx16 o0 = attn_wave<0>(kls, vtl, q00, q01, m31, l5, pi0, pj0);
  const floatx16 o1 = attn_wave<2>(kls, vtl, q10, q11, m31, l5, pi1, pj1);
  __syncthreads();   // all kls/vtl reads complete -> regions reusable

  // ---- at tile -> LDS (dead K region); rows = pixels, cols = dims ----
  _Float16* at_s = sm;
#pragma unroll
  for (int reg = 0; reg < 16; ++reg) {
    const int rowM = (reg & 3) + 8 * (reg >> 2) + 4 * l5;
    at_s[rowM * WSTRIDE + h * 32 + m31] = (_Float16)o0[reg];
    at_s[(32 + rowM) * WSTRIDE + h * 32 + m31] = (_Float16)o1[reg];
  }
  // ---- Wproj -> LDS fp16 (dead V region), cooperative 256 threads ----
  _Float16* wsh = sm + VBASE;
  stage_rows_f16(p.Wproj, wsh, tid);
  stage_rows_f16(p.Wproj + 64 * 128, wsh + 64 * WSTRIDE, tid);
  __syncthreads();

  // ---- projection: wave h -> rows h*16..h*16+15, all 128 cols ----
  const int r = lane & 15;
  const int quad = lane >> 4;
  const _Float16* ap = at_s + (h * 16 + r) * WSTRIDE + quad * 8;
  const _Float16* bp = wsh + r * WSTRIDE + quad * 8;
  floatx4 acc[8];
#pragma unroll
  for (int nt = 0; nt < 8; ++nt) acc[nt] = (floatx4){0.f, 0.f, 0.f, 0.f};
#pragma unroll
  for (int kc = 0; kc < 4; ++kc) {
    const half8 a = *(const half8*)(ap + kc * 32);
#pragma unroll
    for (int nt = 0; nt < 8; ++nt) {
      const half8 bf = *(const half8*)(bp + nt * 16 * WSTRIDE + kc * 32);
      acc[nt] = __builtin_amdgcn_mfma_f32_16x16x32_f16(a, bf, acc[nt], 0, 0, 0);
    }
  }

  // ---- store out: C row m = pxt = h*16 + quad*4 + reg ----
  const int rbase = b * 4096 + (ti * 8 + h * 2 + (quad >> 1)) * 64 +
                    tj * 8 + (quad & 1) * 4;
  float bv[8];
#pragma unroll
  for (int nt = 0; nt < 8; ++nt) bv[nt] = p.bproj[nt * 16 + r];
#pragma unroll
  for (int reg = 0; reg < 4; ++reg) {
    float* cp = p.out + (size_t)(rbase + reg) * 128;
#pragma unroll
    for (int nt = 0; nt < 8; ++nt)
      cp[nt * 16 + r] = acc[nt][reg] + bv[nt];
  }
}

// ---------------------------------------------------------------------------
// Workspace: [1 MB, 13 MB) qkv16 [3][16384][128] fp16 planar.
// ---------------------------------------------------------------------------
extern "C" void kernel_launch(void* const* d_in, const int* in_sizes, int n_in,
                              void* d_out, int out_size, void* d_ws, size_t ws_size,
                              hipStream_t stream) {
  char* ws = (char*)d_ws;
  Params hp;
  hp.x     = (const float*)d_in[0];
  hp.ctx   = (const float*)d_in[1];
  hp.Wqkv  = (const float*)d_in[2];
  hp.bqkv  = (const float*)d_in[3];
  hp.A     = (const float*)d_in[4];
  hp.Blora = (const float*)d_in[5];
  hp.Vlora = (const float*)d_in[6];
  hp.g1w   = (const float*)d_in[7];
  hp.g1b   = (const float*)d_in[8];
  hp.g2w   = (const float*)d_in[9];
  hp.g2b   = (const float*)d_in[10];
  hp.Wproj = (const float*)d_in[11];
  hp.bproj = (const float*)d_in[12];
  hp.out   = (float*)d_out;
  hp.qkv16 = (_Float16*)(ws + (1u << 20));
  hp.at16  = (_Float16*)(ws + (14u << 20));

  gemm1_kernel<<<dim3(64, 2, 4), 256, 0, stream>>>(hp);
  attn_proj_kernel<<<256, 256, 0, stream>>>(hp);
}